// Round 1
// baseline (1748.604 us; speedup 1.0000x reference)
//
#include <hip/hip_runtime.h>
#include <math.h>

#define S_LEN 2048
#define D_DIM 512
#define NROWS (8*2048)

__device__ __forceinline__ float4 ld4(const float* p) { return *(const float4*)p; }

static constexpr float EPS_F = 1.1920929e-07f;           // finfo(float32).eps
static constexpr float SCL   = 0.044194173824159216f;    // 1/sqrt(512)

// ---------------------------------------------------------------------------
// Kernel 1: flash attention (single head) + residual + RMSNorm1 -> hout (ws)
// grid (S/32, B) = (64, 8), block 256.
// Per block: 32 query rows. K-tiles of 128 rows, D chunked by 64.
// ---------------------------------------------------------------------------
__global__ __launch_bounds__(256)
void attn_rms1(const float* __restrict__ x, const float* __restrict__ qm,
               const float* __restrict__ km, const float* __restrict__ n1w,
               float* __restrict__ hout)
{
    __shared__ __align__(16) float qch[32 * 68];     // q chunk 32x64 (+pad)
    __shared__ __align__(16) float kxch[128 * 68];   // K (swizzled) / X (row-major) chunk
    __shared__ __align__(16) float stile[32 * 132];  // scores / probabilities 32x128
    __shared__ float mrun[32], lrun[32], alf[32];

    const int t   = threadIdx.x;
    const int bb  = blockIdx.y;
    const int q0g = blockIdx.x * 32;

    const float* xb = x  + (size_t)bb * S_LEN * D_DIM;
    const float* qb = qm + (size_t)bb * S_LEN * D_DIM;
    const float* kb = km + (size_t)bb * S_LEN * D_DIM;

    if (t < 32) { mrun[t] = -1e30f; lrun[t] = 0.0f; }

    // score-phase ids: 8 q-groups x 32 k-threads, thread tile 4q x 4k
    const int ty = t >> 5;    // 0..7  -> q rows ty*4+u
    const int tx = t & 31;    // 0..31 -> k rows tx+32*j
    // PV ids: 16 q-groups (2 rows) x 16 d-threads (1 float4/chunk)
    const int qg = t >> 4;    // 0..15
    const int dt = t & 15;    // 0..15

    float4 o0[8], o1[8];
#pragma unroll
    for (int m = 0; m < 8; ++m) { o0[m] = make_float4(0,0,0,0); o1[m] = make_float4(0,0,0,0); }

    __syncthreads();

    for (int kt = 0; kt < S_LEN / 128; ++kt) {
        const int krow0 = kt * 128;
        float sacc[4][4];
#pragma unroll
        for (int u = 0; u < 4; ++u)
#pragma unroll
            for (int j = 0; j < 4; ++j) sacc[u][j] = 0.0f;

        // ---- QK^T over 8 chunks of 64 d ----
        for (int dc = 0; dc < 8; ++dc) {
            {
                int f = t;
#pragma unroll
                for (int it = 0; it < 2; ++it, f += 256) {   // Q chunk: 512 f4
                    int r = f >> 4, c4 = f & 15;
                    *(float4*)&qch[r*68 + c4*4] =
                        ld4(qb + (size_t)(q0g + r)*D_DIM + dc*64 + c4*4);
                }
                f = t;
#pragma unroll
                for (int it = 0; it < 8; ++it, f += 256) {   // K chunk: 2048 f4, XOR-swizzled
                    int r = f >> 4, c4 = f & 15;
                    int c4s = c4 ^ (4*(r & 3));
                    *(float4*)&kxch[r*68 + c4s*4] =
                        ld4(kb + (size_t)(krow0 + r)*D_DIM + dc*64 + c4*4);
                }
            }
            __syncthreads();
#pragma unroll 4
            for (int i = 0; i < 16; ++i) {
                float4 qv[4], kv[4];
#pragma unroll
                for (int u = 0; u < 4; ++u)
                    qv[u] = *(const float4*)&qch[(ty*4+u)*68 + i*4];
                const int ci = (i ^ (4*(tx & 3)));
#pragma unroll
                for (int j = 0; j < 4; ++j)
                    kv[j] = *(const float4*)&kxch[(tx + 32*j)*68 + ci*4];
#pragma unroll
                for (int u = 0; u < 4; ++u)
#pragma unroll
                    for (int j = 0; j < 4; ++j)
                        sacc[u][j] += qv[u].x*kv[j].x + qv[u].y*kv[j].y
                                    + qv[u].z*kv[j].z + qv[u].w*kv[j].w;
            }
            __syncthreads();
        }

        // ---- scores -> stile (scaled) ----
#pragma unroll
        for (int u = 0; u < 4; ++u)
#pragma unroll
            for (int j = 0; j < 4; ++j)
                stile[(ty*4+u)*132 + tx + 32*j] = sacc[u][j] * SCL;
        __syncthreads();

        // ---- online softmax update (8 lanes per row) ----
        {
            const int r = t >> 3, lc = t & 7;
            float v[16];
            float mx = -1e30f;
#pragma unroll
            for (int g4 = 0; g4 < 4; ++g4) {
                float4 pv = *(const float4*)&stile[r*132 + (lc*4 + g4)*4];
                v[g4*4+0] = pv.x; v[g4*4+1] = pv.y; v[g4*4+2] = pv.z; v[g4*4+3] = pv.w;
                mx = fmaxf(mx, fmaxf(fmaxf(pv.x, pv.y), fmaxf(pv.z, pv.w)));
            }
#pragma unroll
            for (int w = 1; w < 8; w <<= 1) mx = fmaxf(mx, __shfl_xor(mx, w));
            const float mo = mrun[r];
            const float mn = fmaxf(mo, mx);
            const float al = __expf(mo - mn);
            float sum = 0.0f;
#pragma unroll
            for (int u = 0; u < 16; ++u) { v[u] = __expf(v[u] - mn); sum += v[u]; }
#pragma unroll
            for (int g4 = 0; g4 < 4; ++g4) {
                float4 pv = make_float4(v[g4*4+0], v[g4*4+1], v[g4*4+2], v[g4*4+3]);
                *(float4*)&stile[r*132 + (lc*4 + g4)*4] = pv;
            }
#pragma unroll
            for (int w = 1; w < 8; w <<= 1) sum += __shfl_xor(sum, w);
            if (lc == 0) { mrun[r] = mn; lrun[r] = lrun[r]*al + sum; alf[r] = al; }
        }
        __syncthreads();

        // ---- rescale O ----
        const float al0 = alf[qg*2], al1 = alf[qg*2 + 1];
#pragma unroll
        for (int m = 0; m < 8; ++m) {
            o0[m].x *= al0; o0[m].y *= al0; o0[m].z *= al0; o0[m].w *= al0;
            o1[m].x *= al1; o1[m].y *= al1; o1[m].z *= al1; o1[m].w *= al1;
        }

        // ---- PV over 8 chunks of 64 d ----
        for (int dc = 0; dc < 8; ++dc) {
            int f = t;
#pragma unroll
            for (int it = 0; it < 8; ++it, f += 256) {   // X chunk: row-major, no swizzle
                int r = f >> 4, c4 = f & 15;
                *(float4*)&kxch[r*68 + c4*4] =
                    ld4(xb + (size_t)(krow0 + r)*D_DIM + dc*64 + c4*4);
            }
            __syncthreads();
            float4 acc0 = o0[dc], acc1 = o1[dc];
            const int q0 = qg*2;
#pragma unroll 2
            for (int g = 0; g < 32; ++g) {
                float4 p4a = *(const float4*)&stile[q0*132 + g*4];
                float4 p4b = *(const float4*)&stile[(q0+1)*132 + g*4];
                float pa[4] = {p4a.x, p4a.y, p4a.z, p4a.w};
                float pb[4] = {p4b.x, p4b.y, p4b.z, p4b.w};
#pragma unroll
                for (int kk = 0; kk < 4; ++kk) {
                    float4 xv = *(const float4*)&kxch[(g*4+kk)*68 + dt*4];
                    acc0.x += pa[kk]*xv.x; acc0.y += pa[kk]*xv.y;
                    acc0.z += pa[kk]*xv.z; acc0.w += pa[kk]*xv.w;
                    acc1.x += pb[kk]*xv.x; acc1.y += pb[kk]*xv.y;
                    acc1.z += pb[kk]*xv.z; acc1.w += pb[kk]*xv.w;
                }
            }
            o0[dc] = acc0; o1[dc] = acc1;
            __syncthreads();
        }
    }

    // ---- epilogue: attn = O/l; h = rmsnorm(x + attn) * w1 ----
    const float il0 = 1.0f / lrun[qg*2];
    const float il1 = 1.0f / lrun[qg*2 + 1];
    const int row0 = q0g + qg*2;
    float4 h0[8], h1[8];
    float ss0 = 0.0f, ss1 = 0.0f;
#pragma unroll
    for (int m = 0; m < 8; ++m) {
        const int c4 = 16*m + dt;
        float4 xv0 = ld4(xb + (size_t)row0*D_DIM + c4*4);
        float4 xv1 = ld4(xb + (size_t)(row0+1)*D_DIM + c4*4);
        h0[m].x = xv0.x + o0[m].x*il0; h0[m].y = xv0.y + o0[m].y*il0;
        h0[m].z = xv0.z + o0[m].z*il0; h0[m].w = xv0.w + o0[m].w*il0;
        h1[m].x = xv1.x + o1[m].x*il1; h1[m].y = xv1.y + o1[m].y*il1;
        h1[m].z = xv1.z + o1[m].z*il1; h1[m].w = xv1.w + o1[m].w*il1;
        ss0 += h0[m].x*h0[m].x + h0[m].y*h0[m].y + h0[m].z*h0[m].z + h0[m].w*h0[m].w;
        ss1 += h1[m].x*h1[m].x + h1[m].y*h1[m].y + h1[m].z*h1[m].z + h1[m].w*h1[m].w;
    }
#pragma unroll
    for (int w = 1; w < 16; w <<= 1) {
        ss0 += __shfl_xor(ss0, w);
        ss1 += __shfl_xor(ss1, w);
    }
    const float rr0 = rsqrtf(ss0*(1.0f/512.0f) + EPS_F);
    const float rr1 = rsqrtf(ss1*(1.0f/512.0f) + EPS_F);
    float* hr0 = hout + (size_t)(bb*S_LEN + row0) * D_DIM;
#pragma unroll
    for (int m = 0; m < 8; ++m) {
        const int c4 = 16*m + dt;
        float4 wv = ld4(n1w + c4*4);
        float4 a, b2v;
        a.x = h0[m].x*rr0*wv.x; a.y = h0[m].y*rr0*wv.y;
        a.z = h0[m].z*rr0*wv.z; a.w = h0[m].w*rr0*wv.w;
        b2v.x = h1[m].x*rr1*wv.x; b2v.y = h1[m].y*rr1*wv.y;
        b2v.z = h1[m].z*rr1*wv.z; b2v.w = h1[m].w*rr1*wv.w;
        *(float4*)(hr0 + c4*4)          = a;
        *(float4*)(hr0 + D_DIM + c4*4)  = b2v;
    }
}

// ---------------------------------------------------------------------------
// Kernel 2: proj = h @ W1 + b1; g = gelu(proj[:, :512]) * proj[:, 512:]
// dual-N GEMM: block computes columns [n0,n0+64) and [n0+512,n0+576).
// grid (8, 256), block 256, thread tile 4x4 (x2 N).
// ---------------------------------------------------------------------------
__global__ __launch_bounds__(256)
void ffn1(const float* __restrict__ h, const float* __restrict__ W1,
          const float* __restrict__ b1, float* __restrict__ g)
{
    __shared__ __align__(16) float As [64 * 36];
    __shared__ __align__(16) float Bs1[32 * 64];
    __shared__ __align__(16) float Bs2[32 * 64];
    const int t  = threadIdx.x;
    const int tn = t & 15, tm = t >> 4;
    const int n0 = blockIdx.x * 64, m0 = blockIdx.y * 64;

    float4 acc1[4], acc2[4];
#pragma unroll
    for (int u = 0; u < 4; ++u) { acc1[u] = make_float4(0,0,0,0); acc2[u] = make_float4(0,0,0,0); }

    for (int k0 = 0; k0 < 512; k0 += 32) {
        int f = t;
#pragma unroll
        for (int it = 0; it < 2; ++it, f += 256) {   // A: 64x32
            int r = f >> 3, c4 = f & 7;
            *(float4*)&As[r*36 + c4*4] = ld4(h + (size_t)(m0+r)*512 + k0 + c4*4);
        }
        f = t;
#pragma unroll
        for (int it = 0; it < 2; ++it, f += 256) {   // B: 32x64 (x2)
            int r = f >> 4, c4 = f & 15;
            *(float4*)&Bs1[r*64 + c4*4] = ld4(W1 + (size_t)(k0+r)*1024 + n0 + c4*4);
            *(float4*)&Bs2[r*64 + c4*4] = ld4(W1 + (size_t)(k0+r)*1024 + 512 + n0 + c4*4);
        }
        __syncthreads();
#pragma unroll 8
        for (int kk = 0; kk < 32; ++kk) {
            float4 bv1 = *(const float4*)&Bs1[kk*64 + tn*4];
            float4 bv2 = *(const float4*)&Bs2[kk*64 + tn*4];
#pragma unroll
            for (int u = 0; u < 4; ++u) {
                float a = As[(tm*4+u)*36 + kk];
                acc1[u].x += a*bv1.x; acc1[u].y += a*bv1.y;
                acc1[u].z += a*bv1.z; acc1[u].w += a*bv1.w;
                acc2[u].x += a*bv2.x; acc2[u].y += a*bv2.y;
                acc2[u].z += a*bv2.z; acc2[u].w += a*bv2.w;
            }
        }
        __syncthreads();
    }

    const float4 bb1 = ld4(b1 + n0 + tn*4);
    const float4 bb2 = ld4(b1 + 512 + n0 + tn*4);
#pragma unroll
    for (int u = 0; u < 4; ++u) {
        float c1[4] = {acc1[u].x + bb1.x, acc1[u].y + bb1.y, acc1[u].z + bb1.z, acc1[u].w + bb1.w};
        float c2[4] = {acc2[u].x + bb2.x, acc2[u].y + bb2.y, acc2[u].z + bb2.z, acc2[u].w + bb2.w};
        float4 r;
        float* rp = &r.x;
#pragma unroll
        for (int e = 0; e < 4; ++e) {
            float gl = 0.5f * c1[e] * (1.0f + erff(c1[e] * 0.70710678118654752f));
            rp[e] = gl * c2[e];
        }
        *(float4*)(g + (size_t)(m0 + tm*4 + u)*512 + n0 + tn*4) = r;
    }
}

// ---------------------------------------------------------------------------
// Kernel 3: y = g @ W2 + b2 + h  (written in-place into h buffer)
// dual-N: columns [n0,n0+64) and [n0+256,n0+320). grid (4, 256), block 256.
// ---------------------------------------------------------------------------
__global__ __launch_bounds__(256)
void ffn2(const float* __restrict__ g, const float* __restrict__ W2,
          const float* __restrict__ b2, float* __restrict__ h)
{
    __shared__ __align__(16) float As [64 * 36];
    __shared__ __align__(16) float Bs1[32 * 64];
    __shared__ __align__(16) float Bs2[32 * 64];
    const int t  = threadIdx.x;
    const int tn = t & 15, tm = t >> 4;
    const int n0 = blockIdx.x * 64, m0 = blockIdx.y * 64;

    float4 acc1[4], acc2[4];
#pragma unroll
    for (int u = 0; u < 4; ++u) { acc1[u] = make_float4(0,0,0,0); acc2[u] = make_float4(0,0,0,0); }

    for (int k0 = 0; k0 < 512; k0 += 32) {
        int f = t;
#pragma unroll
        for (int it = 0; it < 2; ++it, f += 256) {
            int r = f >> 3, c4 = f & 7;
            *(float4*)&As[r*36 + c4*4] = ld4(g + (size_t)(m0+r)*512 + k0 + c4*4);
        }
        f = t;
#pragma unroll
        for (int it = 0; it < 2; ++it, f += 256) {
            int r = f >> 4, c4 = f & 15;
            *(float4*)&Bs1[r*64 + c4*4] = ld4(W2 + (size_t)(k0+r)*512 + n0 + c4*4);
            *(float4*)&Bs2[r*64 + c4*4] = ld4(W2 + (size_t)(k0+r)*512 + 256 + n0 + c4*4);
        }
        __syncthreads();
#pragma unroll 8
        for (int kk = 0; kk < 32; ++kk) {
            float4 bv1 = *(const float4*)&Bs1[kk*64 + tn*4];
            float4 bv2 = *(const float4*)&Bs2[kk*64 + tn*4];
#pragma unroll
            for (int u = 0; u < 4; ++u) {
                float a = As[(tm*4+u)*36 + kk];
                acc1[u].x += a*bv1.x; acc1[u].y += a*bv1.y;
                acc1[u].z += a*bv1.z; acc1[u].w += a*bv1.w;
                acc2[u].x += a*bv2.x; acc2[u].y += a*bv2.y;
                acc2[u].z += a*bv2.z; acc2[u].w += a*bv2.w;
            }
        }
        __syncthreads();
    }

    const float4 bb1 = ld4(b2 + n0 + tn*4);
    const float4 bb2 = ld4(b2 + 256 + n0 + tn*4);
#pragma unroll
    for (int u = 0; u < 4; ++u) {
        float* hp1 = h + (size_t)(m0 + tm*4 + u)*512 + n0 + tn*4;
        float* hp2 = hp1 + 256;
        float4 hv1 = ld4(hp1), hv2 = ld4(hp2);
        float4 r1, r2;
        r1.x = acc1[u].x + bb1.x + hv1.x; r1.y = acc1[u].y + bb1.y + hv1.y;
        r1.z = acc1[u].z + bb1.z + hv1.z; r1.w = acc1[u].w + bb1.w + hv1.w;
        r2.x = acc2[u].x + bb2.x + hv2.x; r2.y = acc2[u].y + bb2.y + hv2.y;
        r2.z = acc2[u].z + bb2.z + hv2.z; r2.w = acc2[u].w + bb2.w + hv2.w;
        *(float4*)hp1 = r1;
        *(float4*)hp2 = r2;
    }
}

// ---------------------------------------------------------------------------
// Kernel 4: out = rmsnorm(y) * norm2_w. One wave per row, 4 rows/block.
// ---------------------------------------------------------------------------
__global__ __launch_bounds__(256)
void rms2(const float* __restrict__ y, const float* __restrict__ w2n,
          float* __restrict__ out)
{
    const int wid = threadIdx.x >> 6, lane = threadIdx.x & 63;
    const size_t row = (size_t)blockIdx.x*4 + wid;
    const float* yr = y + row*512;
    float4 a = ld4(yr + lane*4);
    float4 b = ld4(yr + 256 + lane*4);
    float ss = a.x*a.x + a.y*a.y + a.z*a.z + a.w*a.w
             + b.x*b.x + b.y*b.y + b.z*b.z + b.w*b.w;
#pragma unroll
    for (int w = 1; w < 64; w <<= 1) ss += __shfl_xor(ss, w);
    const float r = rsqrtf(ss*(1.0f/512.0f) + EPS_F);
    float4 wa = ld4(w2n + lane*4), wb = ld4(w2n + 256 + lane*4);
    float* orow = out + row*512;
    float4 oa, ob;
    oa.x = a.x*r*wa.x; oa.y = a.y*r*wa.y; oa.z = a.z*r*wa.z; oa.w = a.w*r*wa.w;
    ob.x = b.x*r*wb.x; ob.y = b.y*r*wb.y; ob.z = b.z*r*wb.z; ob.w = b.w*r*wb.w;
    *(float4*)(orow + lane*4)       = oa;
    *(float4*)(orow + 256 + lane*4) = ob;
}

// ---------------------------------------------------------------------------
extern "C" void kernel_launch(void* const* d_in, const int* in_sizes, int n_in,
                              void* d_out, int out_size, void* d_ws, size_t ws_size,
                              hipStream_t stream)
{
    const float* x   = (const float*)d_in[0];
    const float* q   = (const float*)d_in[1];
    const float* k   = (const float*)d_in[2];
    const float* W1  = (const float*)d_in[3];
    const float* b1  = (const float*)d_in[4];
    const float* W2  = (const float*)d_in[5];
    const float* b2  = (const float*)d_in[6];
    const float* n1w = (const float*)d_in[7];
    const float* n2w = (const float*)d_in[8];
    float* out  = (float*)d_out;
    float* hbuf = (float*)d_ws;   // 16384*512 floats = 32 MB
    float* gbuf = out;            // reuse d_out as scratch for g (rewritten by rms2)

    attn_rms1<<<dim3(64, 8),  256, 0, stream>>>(x, q, k, n1w, hbuf);
    ffn1     <<<dim3(8, 256), 256, 0, stream>>>(hbuf, W1, b1, gbuf);
    ffn2     <<<dim3(4, 256), 256, 0, stream>>>(gbuf, W2, b2, hbuf);
    rms2     <<<dim3(4096),   256, 0, stream>>>(hbuf, n2w, out);
}

// Round 2
// 452.595 us; speedup vs baseline: 3.8635x; 3.8635x over previous
//
#include <hip/hip_runtime.h>
#include <math.h>

static constexpr float EPS_F = 1.1920929e-07f;           // finfo(float32).eps
static constexpr float SCL   = 0.044194173824159216f;    // 1/sqrt(512)

typedef __attribute__((ext_vector_type(8))) short  short8;   // 8 bf16 (4 VGPRs)
typedef __attribute__((ext_vector_type(4))) float  floatx4;  // MFMA C/D

__device__ __forceinline__ float4 ld4(const float* p){ return *(const float4*)p; }
__device__ __forceinline__ ushort f2bf(float f){
  union { float f; unsigned u; } v; v.f = f;
  return (ushort)((v.u + 0x7FFFu + ((v.u >> 16) & 1u)) >> 16);   // RNE
}
__device__ __forceinline__ float bf2f(ushort h){
  union { unsigned u; float f; } v; v.u = ((unsigned)h) << 16;
  return v.f;
}
#define MFMA16(A,B,C) __builtin_amdgcn_mfma_f32_16x16x32_bf16((A),(B),(C),0,0,0)

// Frag-layout LDS convention (per 32-k chunk):
//   element (tile_row r, k kk) lives at ushort offset
//   ((r>>4)*64 + (kk>>3)*16 + (r&15))*8 + (kk&7)
// so lane L of group g reads short8 at ((g*64+L)*8):  A[m=L&15][k=(L>>4)*8+j]. Verified layout.

// ---------------------------------------------------------------------------
// Generic transpose + fp32->bf16 cast:  in fp32 [z][R][C] -> out bf16 [z][C][R]
// ---------------------------------------------------------------------------
__global__ __launch_bounds__(256)
void transpose_cvt(const float* __restrict__ in, ushort* __restrict__ out,
                   int R, int C)
{
  __shared__ __align__(16) ushort tile[64*68];
  const int t = threadIdx.x;
  const size_t boff = (size_t)blockIdx.z * R * C;
  const int c0 = blockIdx.x*64, r0 = blockIdx.y*64;
#pragma unroll
  for (int it = 0; it < 4; ++it){
    int f = t + it*256, r = f >> 4, c4 = f & 15;
    float4 v = ld4(in + boff + (size_t)(r0+r)*C + c0 + c4*4);
    ushort4 o; o.x=f2bf(v.x); o.y=f2bf(v.y); o.z=f2bf(v.z); o.w=f2bf(v.w);
    *(ushort4*)&tile[r*68 + c4*4] = o;
  }
  __syncthreads();
#pragma unroll
  for (int it = 0; it < 4; ++it){
    int f = t + it*256, c = f >> 4, q4 = f & 15;
    ushort4 o;
    o.x = tile[(q4*4+0)*68 + c];
    o.y = tile[(q4*4+1)*68 + c];
    o.z = tile[(q4*4+2)*68 + c];
    o.w = tile[(q4*4+3)*68 + c];
    *(ushort4*)(out + boff + (size_t)(c0+c)*R + r0 + q4*4) = o;
  }
}

// ---------------------------------------------------------------------------
// scores[b,q,k] = (Q*SCL) @ K^T   (bf16 out). Block 128x128, 4 waves 64x64.
// grid (2048/128, 2048/128, 8)
// ---------------------------------------------------------------------------
__global__ __launch_bounds__(256)
void qk_gemm(const float* __restrict__ qm, const float* __restrict__ km,
             ushort* __restrict__ scores)
{
  __shared__ __align__(16) ushort Qs[8*64*8];
  __shared__ __align__(16) ushort Ks[8*64*8];
  const int t = threadIdx.x, lane = t & 63, w = t >> 6;
  const int b = blockIdx.z, m0 = blockIdx.y*128, n0 = blockIdx.x*128;
  const float* Qb = qm + (size_t)b*2048*512;
  const float* Kb = km + (size_t)b*2048*512;
  const int sr = t >> 3, sc4 = t & 7;
  const int sbase = ((sc4>>1)*16 + (sr&15))*8 + (sc4&1)*4 + (sr>>4)*512;
  const int ga = (w&1)*4, gb = (w>>1)*4;

  floatx4 acc[4][4];
#pragma unroll
  for (int i=0;i<4;++i)
#pragma unroll
    for (int j=0;j<4;++j) acc[i][j] = (floatx4){0.f,0.f,0.f,0.f};

  float4 qv[4], kv[4];
#pragma unroll
  for (int it=0; it<4; ++it){
    int r = sr + it*32;
    qv[it] = ld4(Qb + (size_t)(m0+r)*512 + sc4*4);
    kv[it] = ld4(Kb + (size_t)(n0+r)*512 + sc4*4);
  }
#pragma unroll
  for (int it=0; it<4; ++it){
    ushort4 a, c;
    a.x=f2bf(qv[it].x*SCL); a.y=f2bf(qv[it].y*SCL); a.z=f2bf(qv[it].z*SCL); a.w=f2bf(qv[it].w*SCL);
    c.x=f2bf(kv[it].x);     c.y=f2bf(kv[it].y);     c.z=f2bf(kv[it].z);     c.w=f2bf(kv[it].w);
    *(ushort4*)&Qs[sbase + it*1024] = a;
    *(ushort4*)&Ks[sbase + it*1024] = c;
  }
  __syncthreads();

  for (int kc = 0; kc < 16; ++kc){
    if (kc < 15){
#pragma unroll
      for (int it=0; it<4; ++it){
        int r = sr + it*32;
        qv[it] = ld4(Qb + (size_t)(m0+r)*512 + (kc+1)*32 + sc4*4);
        kv[it] = ld4(Kb + (size_t)(n0+r)*512 + (kc+1)*32 + sc4*4);
      }
    }
    short8 af[4], bfr[4];
#pragma unroll
    for (int i=0;i<4;++i){
      af[i]  = *(const short8*)&Qs[((ga+i)*64 + lane)*8];
      bfr[i] = *(const short8*)&Ks[((gb+i)*64 + lane)*8];
    }
#pragma unroll
    for (int i=0;i<4;++i)
#pragma unroll
      for (int j=0;j<4;++j)
        acc[i][j] = MFMA16(af[i], bfr[j], acc[i][j]);
    __syncthreads();
    if (kc < 15){
#pragma unroll
      for (int it=0; it<4; ++it){
        ushort4 a, c;
        a.x=f2bf(qv[it].x*SCL); a.y=f2bf(qv[it].y*SCL); a.z=f2bf(qv[it].z*SCL); a.w=f2bf(qv[it].w*SCL);
        c.x=f2bf(kv[it].x);     c.y=f2bf(kv[it].y);     c.z=f2bf(kv[it].z);     c.w=f2bf(kv[it].w);
        *(ushort4*)&Qs[sbase + it*1024] = a;
        *(ushort4*)&Ks[sbase + it*1024] = c;
      }
      __syncthreads();
    }
  }

  const int quad = lane>>4, l15 = lane&15;
  ushort* sb = scores + (size_t)b*2048*2048;
#pragma unroll
  for (int i=0;i<4;++i){
    const int rm = m0 + (ga+i)*16 + quad*4;
#pragma unroll
    for (int j=0;j<4;++j){
      const int cn = n0 + (gb+j)*16 + l15;
#pragma unroll
      for (int r=0;r<4;++r)
        sb[(size_t)(rm+r)*2048 + cn] = f2bf(acc[i][j][r]);
    }
  }
}

// ---------------------------------------------------------------------------
// In-place row softmax over bf16 scores. grid (2048, 8), block 256.
// ---------------------------------------------------------------------------
__global__ __launch_bounds__(256)
void softmax_rows(ushort* __restrict__ sp)
{
  __shared__ float wred[8];
  const int t = threadIdx.x;
  ushort* row = sp + ((size_t)blockIdx.y*2048 + blockIdx.x)*2048;
  ushort4 u0 = *(const ushort4*)&row[t*4];
  ushort4 u1 = *(const ushort4*)&row[1024 + t*4];
  float v[8] = {bf2f(u0.x), bf2f(u0.y), bf2f(u0.z), bf2f(u0.w),
                bf2f(u1.x), bf2f(u1.y), bf2f(u1.z), bf2f(u1.w)};
  float mx = v[0];
#pragma unroll
  for (int e=1;e<8;++e) mx = fmaxf(mx, v[e]);
#pragma unroll
  for (int s=1;s<64;s<<=1) mx = fmaxf(mx, __shfl_xor(mx, s));
  if ((t&63)==0) wred[t>>6] = mx;
  __syncthreads();
  mx = fmaxf(fmaxf(wred[0],wred[1]), fmaxf(wred[2],wred[3]));
  float sum = 0.f;
#pragma unroll
  for (int e=0;e<8;++e){ v[e] = __expf(v[e]-mx); sum += v[e]; }
#pragma unroll
  for (int s=1;s<64;s<<=1) sum += __shfl_xor(sum, s);
  if ((t&63)==0) wred[4 + (t>>6)] = sum;
  __syncthreads();
  const float is = 1.0f/(wred[4]+wred[5]+wred[6]+wred[7]);
  u0.x=f2bf(v[0]*is); u0.y=f2bf(v[1]*is); u0.z=f2bf(v[2]*is); u0.w=f2bf(v[3]*is);
  u1.x=f2bf(v[4]*is); u1.y=f2bf(v[5]*is); u1.z=f2bf(v[6]*is); u1.w=f2bf(v[7]*is);
  *(ushort4*)&row[t*4] = u0;
  *(ushort4*)&row[1024 + t*4] = u1;
}

// ---------------------------------------------------------------------------
// attn_out = P @ X (via XT), o = x + attn_out, h = rmsnorm(o)*n1w -> hbf (bf16)
// Block M=64 x N=512 (full), K=2048. Wave w: all 4 m-groups, d-cols w*128..+128.
// grid (16384/64)
// ---------------------------------------------------------------------------
__global__ __launch_bounds__(256)
void pv_rms1(const ushort* __restrict__ P, const ushort* __restrict__ XT,
             const float* __restrict__ x, const float* __restrict__ n1w,
             ushort* __restrict__ hbf)
{
  __shared__ __align__(16) ushort Ps[4*64*8];
  __shared__ __align__(16) ushort Xs[32*64*8];
  __shared__ float red[64*5];
  const int t = threadIdx.x, lane = t&63, w = t>>6;
  const int m0 = blockIdx.x*64, b = m0 >> 11;
  const ushort* Pb = P  + (size_t)b*2048*2048 + (size_t)(m0 & 2047)*2048;
  const ushort* Xb = XT + (size_t)b*512*2048;
  const int sr = t>>3, sc4 = t&7;
  const int sbase = ((sc4>>1)*16 + (sr&15))*8 + (sc4&1)*4 + (sr>>4)*512;

  floatx4 acc[4][8];
#pragma unroll
  for (int i=0;i<4;++i)
#pragma unroll
    for (int j=0;j<8;++j) acc[i][j] = (floatx4){0.f,0.f,0.f,0.f};

  ushort4 av[2], bv[16];
#pragma unroll
  for (int it=0; it<2; ++it)
    av[it] = *(const ushort4*)&Pb[(size_t)(sr+it*32)*2048 + sc4*4];
#pragma unroll
  for (int it=0; it<16; ++it)
    bv[it] = *(const ushort4*)&Xb[(size_t)(sr+it*32)*2048 + sc4*4];
#pragma unroll
  for (int it=0; it<2; ++it)  *(ushort4*)&Ps[sbase + it*1024] = av[it];
#pragma unroll
  for (int it=0; it<16; ++it) *(ushort4*)&Xs[sbase + it*1024] = bv[it];
  __syncthreads();

  for (int kc = 0; kc < 64; ++kc){
    if (kc < 63){
#pragma unroll
      for (int it=0; it<2; ++it)
        av[it] = *(const ushort4*)&Pb[(size_t)(sr+it*32)*2048 + (kc+1)*32 + sc4*4];
#pragma unroll
      for (int it=0; it<16; ++it)
        bv[it] = *(const ushort4*)&Xb[(size_t)(sr+it*32)*2048 + (kc+1)*32 + sc4*4];
    }
    short8 af[4];
#pragma unroll
    for (int i=0;i<4;++i) af[i] = *(const short8*)&Ps[(i*64 + lane)*8];
#pragma unroll
    for (int j=0;j<8;++j){
      short8 bf8 = *(const short8*)&Xs[((w*8+j)*64 + lane)*8];
#pragma unroll
      for (int i=0;i<4;++i) acc[i][j] = MFMA16(af[i], bf8, acc[i][j]);
    }
    __syncthreads();
    if (kc < 63){
#pragma unroll
      for (int it=0; it<2; ++it)  *(ushort4*)&Ps[sbase + it*1024] = av[it];
#pragma unroll
      for (int it=0; it<16; ++it) *(ushort4*)&Xs[sbase + it*1024] = bv[it];
      __syncthreads();
    }
  }

  // epilogue: residual + rmsnorm1 -> hbf
  const int quad = lane>>4, l15 = lane&15;
  float part[4][4];
#pragma unroll
  for (int mg=0; mg<4; ++mg)
#pragma unroll
    for (int r=0;r<4;++r) part[mg][r] = 0.f;
#pragma unroll
  for (int mg=0; mg<4; ++mg)
#pragma unroll
    for (int j=0; j<8; ++j){
      const int col = w*128 + j*16 + l15;
#pragma unroll
      for (int r=0; r<4; ++r){
        const int row = m0 + mg*16 + quad*4 + r;
        float o = acc[mg][j][r] + x[(size_t)row*512 + col];
        acc[mg][j][r] = o;
        part[mg][r] += o*o;
      }
    }
#pragma unroll
  for (int mg=0; mg<4; ++mg)
#pragma unroll
    for (int r=0;r<4;++r){
      float p = part[mg][r];
      p += __shfl_xor(p,1); p += __shfl_xor(p,2);
      p += __shfl_xor(p,4); p += __shfl_xor(p,8);
      part[mg][r] = p;
    }
  if (l15 == 0){
#pragma unroll
    for (int mg=0; mg<4; ++mg)
#pragma unroll
      for (int r=0;r<4;++r)
        red[(mg*16 + quad*4 + r)*5 + w] = part[mg][r];
  }
  __syncthreads();
#pragma unroll
  for (int mg=0; mg<4; ++mg)
#pragma unroll
    for (int r=0;r<4;++r){
      const int lr = mg*16 + quad*4 + r;
      float tot = red[lr*5] + red[lr*5+1] + red[lr*5+2] + red[lr*5+3];
      part[mg][r] = rsqrtf(tot*(1.0f/512.0f) + EPS_F);
    }
#pragma unroll
  for (int mg=0; mg<4; ++mg)
#pragma unroll
    for (int j=0; j<8; ++j){
      const int col = w*128 + j*16 + l15;
      const float wv = n1w[col];
#pragma unroll
      for (int r=0; r<4; ++r){
        const int row = m0 + mg*16 + quad*4 + r;
        hbf[(size_t)row*512 + col] = f2bf(acc[mg][j][r] * part[mg][r] * wv);
      }
    }
}

// ---------------------------------------------------------------------------
// proj = hbf @ W1 + b1 (via W1T); g = gelu(x1)*x2 -> gbuf (bf16)
// Block M=64 x dual-N 128 (cols n0..n0+128 and 512+n0..+128). grid (4, 256).
// ---------------------------------------------------------------------------
__global__ __launch_bounds__(256)
void ffn1(const ushort* __restrict__ hbf, const ushort* __restrict__ W1T,
          const float* __restrict__ b1, ushort* __restrict__ gbuf)
{
  __shared__ __align__(16) ushort As[4*64*8];
  __shared__ __align__(16) ushort Bs[16*64*8];
  const int t = threadIdx.x, lane=t&63, w=t>>6;
  const int n0 = blockIdx.x*128, m0 = blockIdx.y*64;
  const int sr = t>>3, sc4 = t&7;
  const int sbase = ((sc4>>1)*16 + (sr&15))*8 + (sc4&1)*4 + (sr>>4)*512;

  floatx4 acc[2][8];
#pragma unroll
  for (int i=0;i<2;++i)
#pragma unroll
    for (int j=0;j<8;++j) acc[i][j] = (floatx4){0.f,0.f,0.f,0.f};

  ushort4 av[2], bv[8];
#pragma unroll
  for (int it=0; it<2; ++it)
    av[it] = *(const ushort4*)&hbf[(size_t)(m0+sr+it*32)*512 + sc4*4];
#pragma unroll
  for (int it=0; it<8; ++it){
    int r = sr + it*32;
    int srcr = (r < 128) ? (n0 + r) : (384 + n0 + r);
    bv[it] = *(const ushort4*)&W1T[(size_t)srcr*512 + sc4*4];
  }
#pragma unroll
  for (int it=0; it<2; ++it) *(ushort4*)&As[sbase + it*1024] = av[it];
#pragma unroll
  for (int it=0; it<8; ++it) *(ushort4*)&Bs[sbase + it*1024] = bv[it];
  __syncthreads();

  for (int kc = 0; kc < 16; ++kc){
    if (kc < 15){
#pragma unroll
      for (int it=0; it<2; ++it)
        av[it] = *(const ushort4*)&hbf[(size_t)(m0+sr+it*32)*512 + (kc+1)*32 + sc4*4];
#pragma unroll
      for (int it=0; it<8; ++it){
        int r = sr + it*32;
        int srcr = (r < 128) ? (n0 + r) : (384 + n0 + r);
        bv[it] = *(const ushort4*)&W1T[(size_t)srcr*512 + (kc+1)*32 + sc4*4];
      }
    }
    short8 af[2];
#pragma unroll
    for (int i=0;i<2;++i) af[i] = *(const short8*)&As[(((w&1)*2+i)*64 + lane)*8];
#pragma unroll
    for (int j=0;j<8;++j){
      const int grp = (j<4) ? ((w>>1)*4 + j) : (8 + (w>>1)*4 + (j-4));
      short8 bf8 = *(const short8*)&Bs[(grp*64 + lane)*8];
#pragma unroll
      for (int i=0;i<2;++i) acc[i][j] = MFMA16(af[i], bf8, acc[i][j]);
    }
    __syncthreads();
    if (kc < 15){
#pragma unroll
      for (int it=0; it<2; ++it) *(ushort4*)&As[sbase + it*1024] = av[it];
#pragma unroll
      for (int it=0; it<8; ++it) *(ushort4*)&Bs[sbase + it*1024] = bv[it];
      __syncthreads();
    }
  }

  const int quad = lane>>4, l15 = lane&15;
#pragma unroll
  for (int i=0;i<2;++i){
#pragma unroll
    for (int p=0;p<4;++p){
      const int c1 = n0 + ((w>>1)*4+p)*16 + l15;
      const float bb1 = b1[c1], bb2 = b1[512+c1];
#pragma unroll
      for (int r=0;r<4;++r){
        const int row = m0 + ((w&1)*2+i)*16 + quad*4 + r;
        float x1 = acc[i][p][r]   + bb1;
        float x2 = acc[i][p+4][r] + bb2;
        float gl = 0.5f*x1*(1.0f + erff(x1*0.70710678118654752f));
        gbuf[(size_t)row*512 + c1] = f2bf(gl*x2);
      }
    }
  }
}

// ---------------------------------------------------------------------------
// ff = g @ W2 + b2 (via W2T); y = hbf + ff; out = rmsnorm(y)*n2w  (fp32 out)
// Block M=32 x N=512 (full). grid (16384/32).
// ---------------------------------------------------------------------------
__global__ __launch_bounds__(256)
void ffn2_rms2(const ushort* __restrict__ gb, const ushort* __restrict__ W2T,
               const float* __restrict__ b2, const ushort* __restrict__ hbf,
               const float* __restrict__ n2w, float* __restrict__ out)
{
  __shared__ __align__(16) ushort As[2*64*8];
  __shared__ __align__(16) ushort Bs[32*64*8];
  __shared__ float red[32*5];
  const int t=threadIdx.x, lane=t&63, w=t>>6;
  const int m0 = blockIdx.x*32;
  const int sr=t>>3, sc4=t&7;
  const int sbase = ((sc4>>1)*16 + (sr&15))*8 + (sc4&1)*4 + (sr>>4)*512;

  floatx4 acc[2][8];
#pragma unroll
  for (int i=0;i<2;++i)
#pragma unroll
    for (int j=0;j<8;++j) acc[i][j] = (floatx4){0.f,0.f,0.f,0.f};

  ushort4 av, bv[16];
  av = *(const ushort4*)&gb[(size_t)(m0+sr)*512 + sc4*4];
#pragma unroll
  for (int it=0; it<16; ++it)
    bv[it] = *(const ushort4*)&W2T[(size_t)(sr+it*32)*512 + sc4*4];
  *(ushort4*)&As[sbase] = av;
#pragma unroll
  for (int it=0; it<16; ++it) *(ushort4*)&Bs[sbase + it*1024] = bv[it];
  __syncthreads();

  for (int kc = 0; kc < 16; ++kc){
    if (kc < 15){
      av = *(const ushort4*)&gb[(size_t)(m0+sr)*512 + (kc+1)*32 + sc4*4];
#pragma unroll
      for (int it=0; it<16; ++it)
        bv[it] = *(const ushort4*)&W2T[(size_t)(sr+it*32)*512 + (kc+1)*32 + sc4*4];
    }
    short8 af[2];
#pragma unroll
    for (int i=0;i<2;++i) af[i] = *(const short8*)&As[(i*64 + lane)*8];
#pragma unroll
    for (int j=0;j<8;++j){
      short8 bf8 = *(const short8*)&Bs[((w*8+j)*64 + lane)*8];
#pragma unroll
      for (int i=0;i<2;++i) acc[i][j] = MFMA16(af[i], bf8, acc[i][j]);
    }
    __syncthreads();
    if (kc < 15){
      *(ushort4*)&As[sbase] = av;
#pragma unroll
      for (int it=0; it<16; ++it) *(ushort4*)&Bs[sbase + it*1024] = bv[it];
      __syncthreads();
    }
  }

  const int quad = lane>>4, l15 = lane&15;
  float part[2][4];
#pragma unroll
  for (int i=0;i<2;++i)
#pragma unroll
    for (int r=0;r<4;++r) part[i][r] = 0.f;
#pragma unroll
  for (int i=0;i<2;++i)
#pragma unroll
    for (int j=0;j<8;++j){
      const int col = w*128 + j*16 + l15;
      const float bb = b2[col];
#pragma unroll
      for (int r=0;r<4;++r){
        const int row = m0 + i*16 + quad*4 + r;
        float y = acc[i][j][r] + bb + bf2f(hbf[(size_t)row*512 + col]);
        acc[i][j][r] = y;
        part[i][r] += y*y;
      }
    }
#pragma unroll
  for (int i=0;i<2;++i)
#pragma unroll
    for (int r=0;r<4;++r){
      float p = part[i][r];
      p += __shfl_xor(p,1); p += __shfl_xor(p,2);
      p += __shfl_xor(p,4); p += __shfl_xor(p,8);
      part[i][r] = p;
    }
  if (l15 == 0){
#pragma unroll
    for (int i=0;i<2;++i)
#pragma unroll
      for (int r=0;r<4;++r)
        red[(i*16 + quad*4 + r)*5 + w] = part[i][r];
  }
  __syncthreads();
#pragma unroll
  for (int i=0;i<2;++i)
#pragma unroll
    for (int r=0;r<4;++r){
      const int lr = i*16 + quad*4 + r;
      float tot = red[lr*5] + red[lr*5+1] + red[lr*5+2] + red[lr*5+3];
      part[i][r] = rsqrtf(tot*(1.0f/512.0f) + EPS_F);
    }
#pragma unroll
  for (int i=0;i<2;++i)
#pragma unroll
    for (int j=0;j<8;++j){
      const int col = w*128 + j*16 + l15;
      const float wv = n2w[col];
#pragma unroll
      for (int r=0;r<4;++r){
        const int row = m0 + i*16 + quad*4 + r;
        out[(size_t)row*512 + col] = acc[i][j][r] * part[i][r] * wv;
      }
    }
}

// ---------------------------------------------------------------------------
extern "C" void kernel_launch(void* const* d_in, const int* in_sizes, int n_in,
                              void* d_out, int out_size, void* d_ws, size_t ws_size,
                              hipStream_t stream)
{
  const float* x   = (const float*)d_in[0];
  const float* q   = (const float*)d_in[1];
  const float* k   = (const float*)d_in[2];
  const float* W1  = (const float*)d_in[3];
  const float* b1  = (const float*)d_in[4];
  const float* W2  = (const float*)d_in[5];
  const float* b2  = (const float*)d_in[6];
  const float* n1w = (const float*)d_in[7];
  const float* n2w = (const float*)d_in[8];
  float* out = (float*)d_out;

  // ws layout (ushort units): scores/P 64MB | XT 16MB | hbf 16MB | W1T 1MB | W2T 0.5MB
  ushort* scoresP = (ushort*)d_ws;
  ushort* XT  = scoresP + (size_t)8*2048*2048;
  ushort* hb  = XT + (size_t)8*512*2048;
  ushort* W1T = hb + (size_t)16384*512;
  ushort* W2T = W1T + (size_t)1024*512;
  ushort* gbuf = scoresP;   // reuse: P dead after pv_rms1

  transpose_cvt<<<dim3(8, 32, 8), 256, 0, stream>>>(x,  XT,  2048, 512);
  transpose_cvt<<<dim3(16, 8, 1), 256, 0, stream>>>(W1, W1T, 512, 1024);
  transpose_cvt<<<dim3(8,  8, 1), 256, 0, stream>>>(W2, W2T, 512, 512);

  qk_gemm     <<<dim3(16, 16, 8), 256, 0, stream>>>(q, k, scoresP);
  softmax_rows<<<dim3(2048, 8),   256, 0, stream>>>(scoresP);
  pv_rms1     <<<dim3(256),       256, 0, stream>>>(scoresP, XT, x, n1w, hb);
  ffn1        <<<dim3(4, 256),    256, 0, stream>>>(hb, W1T, b1, gbuf);
  ffn2_rms2   <<<dim3(512),       256, 0, stream>>>(gbuf, W2T, b2, hb, n2w, out);
}

// Round 3
// 365.356 us; speedup vs baseline: 4.7860x; 1.2388x over previous
//
#include <hip/hip_runtime.h>
#include <math.h>

static constexpr float EPS_F = 1.1920929e-07f;           // finfo(float32).eps
static constexpr float SCL   = 0.044194173824159216f;    // 1/sqrt(512)

typedef __attribute__((ext_vector_type(8))) short  short8;   // 8 bf16 (4 VGPRs)
typedef __attribute__((ext_vector_type(4))) float  floatx4;  // MFMA C/D

__device__ __forceinline__ float4 ld4(const float* p){ return *(const float4*)p; }
__device__ __forceinline__ ushort f2bf(float f){
  union { float f; unsigned u; } v; v.f = f;
  return (ushort)((v.u + 0x7FFFu + ((v.u >> 16) & 1u)) >> 16);   // RNE
}
__device__ __forceinline__ float bf2f(ushort h){
  union { unsigned u; float f; } v; v.u = ((unsigned)h) << 16;
  return v.f;
}
#define MFMA16(A,B,C) __builtin_amdgcn_mfma_f32_16x16x32_bf16((A),(B),(C),0,0,0)

// async global->LDS, 16B per lane. LDS dst = wave-uniform base + lane*16.
__device__ __forceinline__ void gld16(void* lds, const void* g){
  __builtin_amdgcn_global_load_lds(
      (const __attribute__((address_space(1))) unsigned int*)g,
      (__attribute__((address_space(3))) unsigned int*)lds, 16, 0, 0);
}

// LDS tile layout: row-major [rows][32] bf16 (64 B/row). Staging lane L of an
// issue covers row base+L/4, k-chunk (L%4)*8 — contiguous, matches gld16.
// A/B frag read: lane L -> element [m=16*g+(L&15)][k=(L>>4)*8+j], one ds_read_b128.

// ---------------------------------------------------------------------------
// cvt_qk: Qbf = bf16(q*SCL), Kbf = bf16(k). grid 8192, block 256.
// ---------------------------------------------------------------------------
__global__ __launch_bounds__(256)
void cvt_qk(const float* __restrict__ q, const float* __restrict__ k,
            ushort* __restrict__ Qb, ushort* __restrict__ Kb)
{
  const size_t i4 = ((size_t)blockIdx.x*256 + threadIdx.x)*4;
  float4 v = ld4(q + i4);
  ushort4 o;
  o.x=f2bf(v.x*SCL); o.y=f2bf(v.y*SCL); o.z=f2bf(v.z*SCL); o.w=f2bf(v.w*SCL);
  *(ushort4*)(Qb + i4) = o;
  float4 u = ld4(k + i4);
  o.x=f2bf(u.x); o.y=f2bf(u.y); o.z=f2bf(u.z); o.w=f2bf(u.w);
  *(ushort4*)(Kb + i4) = o;
}

// ---------------------------------------------------------------------------
// transpose + cast: fp32 [z][R][C] -> bf16 [z][C][R]
// ---------------------------------------------------------------------------
__global__ __launch_bounds__(256)
void transpose_cvt(const float* __restrict__ in, ushort* __restrict__ out,
                   int R, int C)
{
  __shared__ __align__(16) ushort tile[64*68];
  const int t = threadIdx.x;
  const size_t boff = (size_t)blockIdx.z * R * C;
  const int c0 = blockIdx.x*64, r0 = blockIdx.y*64;
#pragma unroll
  for (int it = 0; it < 4; ++it){
    int f = t + it*256, r = f >> 4, c4 = f & 15;
    float4 v = ld4(in + boff + (size_t)(r0+r)*C + c0 + c4*4);
    ushort4 o; o.x=f2bf(v.x); o.y=f2bf(v.y); o.z=f2bf(v.z); o.w=f2bf(v.w);
    *(ushort4*)&tile[r*68 + c4*4] = o;
  }
  __syncthreads();
#pragma unroll
  for (int it = 0; it < 4; ++it){
    int f = t + it*256, c = f >> 4, q4 = f & 15;
    ushort4 o;
    o.x = tile[(q4*4+0)*68 + c];
    o.y = tile[(q4*4+1)*68 + c];
    o.z = tile[(q4*4+2)*68 + c];
    o.w = tile[(q4*4+3)*68 + c];
    *(ushort4*)(out + boff + (size_t)(c0+c)*R + r0 + q4*4) = o;
  }
}

// ---------------------------------------------------------------------------
// qk_gemm: scores = Qbf @ Kbf^T (bf16). 128x128 tile, BK=32, m97 structure.
// grid (16,16,8), block 256 (4 waves 2x2).
// ---------------------------------------------------------------------------
__global__ __launch_bounds__(256)
void qk_gemm(const ushort* __restrict__ Qbf, const ushort* __restrict__ Kbf,
             ushort* __restrict__ scores)
{
  __shared__ __align__(16) ushort As[128*32];
  __shared__ __align__(16) ushort Bs[128*32];
  const int t=threadIdx.x, lane=t&63, w=t>>6;
  const int b=blockIdx.z, m0=blockIdx.y*128, n0=blockIdx.x*128;
  const ushort* Qb = Qbf + ((size_t)b*2048 + m0)*512;
  const ushort* Kb = Kbf + ((size_t)b*2048 + n0)*512;
  const int sr = w*32 + (lane>>2);     // staging row (this issue covers 16 rows)
  const int sc = (lane&3)*8;           // staging ushort col
  const int ga=(w&1)*4, gb2=(w>>1)*4;
  const int l15=lane&15, quad=lane>>4;

  floatx4 acc[4][4];
#pragma unroll
  for (int i=0;i<4;++i)
#pragma unroll
    for (int j=0;j<4;++j) acc[i][j]=(floatx4){0.f,0.f,0.f,0.f};

  for (int kc=0; kc<16; ++kc){
    const int k0 = kc*32;
    gld16(&As[(w*32)*32],    Qb + (size_t)sr*512      + k0 + sc);
    gld16(&As[(w*32+16)*32], Qb + (size_t)(sr+16)*512 + k0 + sc);
    gld16(&Bs[(w*32)*32],    Kb + (size_t)sr*512      + k0 + sc);
    gld16(&Bs[(w*32+16)*32], Kb + (size_t)(sr+16)*512 + k0 + sc);
    __syncthreads();
    short8 af[4], bfr[4];
#pragma unroll
    for (int i=0;i<4;++i) af[i]  = *(const short8*)&As[((ga+i)*16 + l15)*32 + quad*8];
#pragma unroll
    for (int j=0;j<4;++j) bfr[j] = *(const short8*)&Bs[((gb2+j)*16 + l15)*32 + quad*8];
#pragma unroll
    for (int i=0;i<4;++i)
#pragma unroll
      for (int j=0;j<4;++j)
        acc[i][j] = MFMA16(af[i], bfr[j], acc[i][j]);
    __syncthreads();
  }

  ushort* sb = scores + (size_t)b*2048*2048;
#pragma unroll
  for (int i=0;i<4;++i){
    const int rm = m0 + (ga+i)*16 + quad*4;
#pragma unroll
    for (int j=0;j<4;++j){
      const int cn = n0 + (gb2+j)*16 + l15;
#pragma unroll
      for (int r=0;r<4;++r)
        sb[(size_t)(rm+r)*2048 + cn] = f2bf(acc[i][j][r]);
    }
  }
}

// ---------------------------------------------------------------------------
// softmax over bf16 score rows, in place. grid (2048,8), block 256.
// ---------------------------------------------------------------------------
__global__ __launch_bounds__(256)
void softmax_rows(ushort* __restrict__ sp)
{
  __shared__ float wred[8];
  const int t = threadIdx.x;
  ushort* row = sp + ((size_t)blockIdx.y*2048 + blockIdx.x)*2048;
  ushort4 u0 = *(const ushort4*)&row[t*4];
  ushort4 u1 = *(const ushort4*)&row[1024 + t*4];
  float v[8] = {bf2f(u0.x), bf2f(u0.y), bf2f(u0.z), bf2f(u0.w),
                bf2f(u1.x), bf2f(u1.y), bf2f(u1.z), bf2f(u1.w)};
  float mx = v[0];
#pragma unroll
  for (int e=1;e<8;++e) mx = fmaxf(mx, v[e]);
#pragma unroll
  for (int s=1;s<64;s<<=1) mx = fmaxf(mx, __shfl_xor(mx, s));
  if ((t&63)==0) wred[t>>6] = mx;
  __syncthreads();
  mx = fmaxf(fmaxf(wred[0],wred[1]), fmaxf(wred[2],wred[3]));
  float sum = 0.f;
#pragma unroll
  for (int e=0;e<8;++e){ v[e] = __expf(v[e]-mx); sum += v[e]; }
#pragma unroll
  for (int s=1;s<64;s<<=1) sum += __shfl_xor(sum, s);
  if ((t&63)==0) wred[4 + (t>>6)] = sum;
  __syncthreads();
  const float is = 1.0f/(wred[4]+wred[5]+wred[6]+wred[7]);
  u0.x=f2bf(v[0]*is); u0.y=f2bf(v[1]*is); u0.z=f2bf(v[2]*is); u0.w=f2bf(v[3]*is);
  u1.x=f2bf(v[4]*is); u1.y=f2bf(v[5]*is); u1.z=f2bf(v[6]*is); u1.w=f2bf(v[7]*is);
  *(ushort4*)&row[t*4] = u0;
  *(ushort4*)&row[1024 + t*4] = u1;
}

// ---------------------------------------------------------------------------
// pv_rms1: attn = P @ X (XT), h = rmsnorm(x + attn)*n1w -> hbf (bf16)
// M=64 x N=512(full) per block, K=2048, BK=32. block 512 (8 waves, n=64 each).
// grid 256.
// ---------------------------------------------------------------------------
__global__ __launch_bounds__(512)
void pv_rms1(const ushort* __restrict__ P, const ushort* __restrict__ XT,
             const float* __restrict__ x, const float* __restrict__ n1w,
             ushort* __restrict__ hbf)
{
  __shared__ __align__(16) ushort Ps[64*32];    // 4 KB
  __shared__ __align__(16) ushort Xs[512*32];   // 32 KB
  __shared__ float red[64*8];
  const int t=threadIdx.x, lane=t&63, w=t>>6;   // w 0..7
  const int m0=blockIdx.x*64, b=m0>>11, lm=m0&2047;
  const ushort* Pb = P  + ((size_t)b*2048 + lm)*2048;
  const ushort* Xb = XT + (size_t)b*512*2048;
  const int srq = lane>>2, sc=(lane&3)*8;
  const int l15=lane&15, quad=lane>>4;

  floatx4 acc[4][4];
#pragma unroll
  for (int i=0;i<4;++i)
#pragma unroll
    for (int j=0;j<4;++j) acc[i][j]=(floatx4){0.f,0.f,0.f,0.f};

  for (int kc=0; kc<64; ++kc){
    const int k0 = kc*32;
    if (w < 4)
      gld16(&Ps[(w*16)*32], Pb + (size_t)(w*16+srq)*2048 + k0 + sc);
#pragma unroll
    for (int i2=0;i2<4;++i2)
      gld16(&Xs[(w*64+i2*16)*32], Xb + (size_t)(w*64+i2*16+srq)*2048 + k0 + sc);
    __syncthreads();
    short8 af[4], bfr[4];
#pragma unroll
    for (int i=0;i<4;++i) af[i]  = *(const short8*)&Ps[(i*16 + l15)*32 + quad*8];
#pragma unroll
    for (int j=0;j<4;++j) bfr[j] = *(const short8*)&Xs[((w*4+j)*16 + l15)*32 + quad*8];
#pragma unroll
    for (int i=0;i<4;++i)
#pragma unroll
      for (int j=0;j<4;++j)
        acc[i][j] = MFMA16(af[i], bfr[j], acc[i][j]);
    __syncthreads();
  }

  // epilogue: residual + RMSNorm1
  float part[4][4];
#pragma unroll
  for (int i=0;i<4;++i)
#pragma unroll
    for (int r=0;r<4;++r) part[i][r]=0.f;
#pragma unroll
  for (int i=0;i<4;++i)
#pragma unroll
    for (int j=0;j<4;++j){
      const int col = w*64 + j*16 + l15;
#pragma unroll
      for (int r=0;r<4;++r){
        const int row = m0 + i*16 + quad*4 + r;
        float o = acc[i][j][r] + x[(size_t)row*512 + col];
        acc[i][j][r] = o;
        part[i][r] += o*o;
      }
    }
#pragma unroll
  for (int i=0;i<4;++i)
#pragma unroll
    for (int r=0;r<4;++r){
      float p = part[i][r];
      p += __shfl_xor(p,1); p += __shfl_xor(p,2);
      p += __shfl_xor(p,4); p += __shfl_xor(p,8);
      part[i][r] = p;
    }
  if (l15 == 0){
#pragma unroll
    for (int i=0;i<4;++i)
#pragma unroll
      for (int r=0;r<4;++r)
        red[(i*16 + quad*4 + r)*8 + w] = part[i][r];
  }
  __syncthreads();
#pragma unroll
  for (int i=0;i<4;++i)
#pragma unroll
    for (int r=0;r<4;++r){
      const int lr = i*16 + quad*4 + r;
      float tot = red[lr*8]+red[lr*8+1]+red[lr*8+2]+red[lr*8+3]
                + red[lr*8+4]+red[lr*8+5]+red[lr*8+6]+red[lr*8+7];
      part[i][r] = rsqrtf(tot*(1.0f/512.0f) + EPS_F);
    }
#pragma unroll
  for (int i=0;i<4;++i)
#pragma unroll
    for (int j=0;j<4;++j){
      const int col = w*64 + j*16 + l15;
      const float wv = n1w[col];
#pragma unroll
      for (int r=0;r<4;++r){
        const int row = m0 + i*16 + quad*4 + r;
        hbf[(size_t)row*512 + col] = f2bf(acc[i][j][r] * part[i][r] * wv);
      }
    }
}

// ---------------------------------------------------------------------------
// ffn1: proj = hbf @ W1 + b1 (W1T), g = gelu(x1)*x2 -> gbuf (bf16)
// 128m x dual-64n (cols n0.. and 512+n0..), BK=32. grid (8,128), block 256.
// ---------------------------------------------------------------------------
__global__ __launch_bounds__(256)
void ffn1(const ushort* __restrict__ hbf, const ushort* __restrict__ W1T,
          const float* __restrict__ b1, ushort* __restrict__ gbuf)
{
  __shared__ __align__(16) ushort As[128*32];
  __shared__ __align__(16) ushort Bs[128*32];
  const int t=threadIdx.x, lane=t&63, w=t>>6;
  const int n0=blockIdx.x*64, m0=blockIdx.y*128;
  const int sr = w*32 + (lane>>2), sc=(lane&3)*8;
  const int ga=(w&1)*4, b2=(w>>1);
  const int l15=lane&15, quad=lane>>4;
  // B-tile rows 0..63 = W1T rows n0+r (x1); rows 64..127 = W1T rows 448+n0+r (x2)
  const int gr0 = (sr < 64) ? (n0+sr) : (448+n0+sr);
  const int sr1 = sr+16;
  const int gr1 = (sr1 < 64) ? (n0+sr1) : (448+n0+sr1);

  floatx4 acc[4][4];
#pragma unroll
  for (int i=0;i<4;++i)
#pragma unroll
    for (int j=0;j<4;++j) acc[i][j]=(floatx4){0.f,0.f,0.f,0.f};

  for (int kc=0; kc<16; ++kc){
    const int k0 = kc*32;
    gld16(&As[(w*32)*32],    hbf + (size_t)(m0+sr)*512  + k0 + sc);
    gld16(&As[(w*32+16)*32], hbf + (size_t)(m0+sr1)*512 + k0 + sc);
    gld16(&Bs[(w*32)*32],    W1T + (size_t)gr0*512 + k0 + sc);
    gld16(&Bs[(w*32+16)*32], W1T + (size_t)gr1*512 + k0 + sc);
    __syncthreads();
    short8 af[4], bfr[4];
#pragma unroll
    for (int i=0;i<4;++i) af[i] = *(const short8*)&As[((ga+i)*16 + l15)*32 + quad*8];
#pragma unroll
    for (int jj=0;jj<4;++jj){
      const int g1 = (jj<2) ? (b2*2+jj) : (4 + b2*2 + (jj-2));
      bfr[jj] = *(const short8*)&Bs[(g1*16 + l15)*32 + quad*8];
    }
#pragma unroll
    for (int i=0;i<4;++i)
#pragma unroll
      for (int jj=0;jj<4;++jj)
        acc[i][jj] = MFMA16(af[i], bfr[jj], acc[i][jj]);
    __syncthreads();
  }

#pragma unroll
  for (int i=0;i<4;++i){
#pragma unroll
    for (int jj=0;jj<2;++jj){
      const int col = n0 + (b2*2+jj)*16 + l15;
      const float bb1 = b1[col], bb2 = b1[512+col];
#pragma unroll
      for (int r=0;r<4;++r){
        const int row = m0 + (ga+i)*16 + quad*4 + r;
        float x1 = acc[i][jj][r]   + bb1;
        float x2 = acc[i][jj+2][r] + bb2;
        float gl = 0.5f*x1*(1.0f + erff(x1*0.70710678118654752f));
        gbuf[(size_t)row*512 + col] = f2bf(gl*x2);
      }
    }
  }
}

// ---------------------------------------------------------------------------
// ffn2_rms2: y = g @ W2 + b2 + h; out = rmsnorm(y)*n2w (fp32)
// M=64 x N=512(full), K=512, BK=32. block 512 (8 waves). grid 256.
// ---------------------------------------------------------------------------
__global__ __launch_bounds__(512)
void ffn2_rms2(const ushort* __restrict__ gb, const ushort* __restrict__ W2T,
               const float* __restrict__ b2, const ushort* __restrict__ hbf,
               const float* __restrict__ n2w, float* __restrict__ out)
{
  __shared__ __align__(16) ushort As[64*32];
  __shared__ __align__(16) ushort Bs[512*32];
  __shared__ float red[64*8];
  const int t=threadIdx.x, lane=t&63, w=t>>6;
  const int m0=blockIdx.x*64;
  const int srq = lane>>2, sc=(lane&3)*8;
  const int l15=lane&15, quad=lane>>4;

  floatx4 acc[4][4];
#pragma unroll
  for (int i=0;i<4;++i)
#pragma unroll
    for (int j=0;j<4;++j) acc[i][j]=(floatx4){0.f,0.f,0.f,0.f};

  for (int kc=0; kc<16; ++kc){
    const int k0 = kc*32;
    if (w < 4)
      gld16(&As[(w*16)*32], gb + (size_t)(m0+w*16+srq)*512 + k0 + sc);
#pragma unroll
    for (int i2=0;i2<4;++i2)
      gld16(&Bs[(w*64+i2*16)*32], W2T + (size_t)(w*64+i2*16+srq)*512 + k0 + sc);
    __syncthreads();
    short8 af[4], bfr[4];
#pragma unroll
    for (int i=0;i<4;++i) af[i]  = *(const short8*)&As[(i*16 + l15)*32 + quad*8];
#pragma unroll
    for (int j=0;j<4;++j) bfr[j] = *(const short8*)&Bs[((w*4+j)*16 + l15)*32 + quad*8];
#pragma unroll
    for (int i=0;i<4;++i)
#pragma unroll
      for (int j=0;j<4;++j)
        acc[i][j] = MFMA16(af[i], bfr[j], acc[i][j]);
    __syncthreads();
  }

  float part[4][4];
#pragma unroll
  for (int i=0;i<4;++i)
#pragma unroll
    for (int r=0;r<4;++r) part[i][r]=0.f;
#pragma unroll
  for (int i=0;i<4;++i)
#pragma unroll
    for (int j=0;j<4;++j){
      const int col = w*64 + j*16 + l15;
      const float bb = b2[col];
#pragma unroll
      for (int r=0;r<4;++r){
        const int row = m0 + i*16 + quad*4 + r;
        float y = acc[i][j][r] + bb + bf2f(hbf[(size_t)row*512 + col]);
        acc[i][j][r] = y;
        part[i][r] += y*y;
      }
    }
#pragma unroll
  for (int i=0;i<4;++i)
#pragma unroll
    for (int r=0;r<4;++r){
      float p = part[i][r];
      p += __shfl_xor(p,1); p += __shfl_xor(p,2);
      p += __shfl_xor(p,4); p += __shfl_xor(p,8);
      part[i][r] = p;
    }
  if (l15 == 0){
#pragma unroll
    for (int i=0;i<4;++i)
#pragma unroll
      for (int r=0;r<4;++r)
        red[(i*16 + quad*4 + r)*8 + w] = part[i][r];
  }
  __syncthreads();
#pragma unroll
  for (int i=0;i<4;++i)
#pragma unroll
    for (int r=0;r<4;++r){
      const int lr = i*16 + quad*4 + r;
      float tot = red[lr*8]+red[lr*8+1]+red[lr*8+2]+red[lr*8+3]
                + red[lr*8+4]+red[lr*8+5]+red[lr*8+6]+red[lr*8+7];
      part[i][r] = rsqrtf(tot*(1.0f/512.0f) + EPS_F);
    }
#pragma unroll
  for (int i=0;i<4;++i)
#pragma unroll
    for (int j=0;j<4;++j){
      const int col = w*64 + j*16 + l15;
      const float wv = n2w[col];
#pragma unroll
      for (int r=0;r<4;++r){
        const int row = m0 + i*16 + quad*4 + r;
        out[(size_t)row*512 + col] = acc[i][j][r] * part[i][r] * wv;
      }
    }
}

// ---------------------------------------------------------------------------
extern "C" void kernel_launch(void* const* d_in, const int* in_sizes, int n_in,
                              void* d_out, int out_size, void* d_ws, size_t ws_size,
                              hipStream_t stream)
{
  const float* x   = (const float*)d_in[0];
  const float* q   = (const float*)d_in[1];
  const float* k   = (const float*)d_in[2];
  const float* W1  = (const float*)d_in[3];
  const float* b1  = (const float*)d_in[4];
  const float* W2  = (const float*)d_in[5];
  const float* b2  = (const float*)d_in[6];
  const float* n1w = (const float*)d_in[7];
  const float* n2w = (const float*)d_in[8];
  float* out = (float*)d_out;

  // ws (ushort units): scores 64MB | XT 16MB | Qbf 16MB | Kbf 16MB | W1T 1MB | W2T .5MB
  ushort* scoresP = (ushort*)d_ws;
  ushort* XT  = scoresP + (size_t)8*2048*2048;
  ushort* Qbf = XT  + (size_t)8*512*2048;
  ushort* Kbf = Qbf + (size_t)8*2048*512;
  ushort* W1T = Kbf + (size_t)8*2048*512;
  ushort* W2T = W1T + (size_t)1024*512;
  ushort* hbf  = Qbf;   // alias: Qbf dead after qk_gemm
  ushort* gbuf = Kbf;   // alias: Kbf dead after qk_gemm

  cvt_qk       <<<dim3(8192),     256, 0, stream>>>(q, k, Qbf, Kbf);
  transpose_cvt<<<dim3(8, 32, 8), 256, 0, stream>>>(x,  XT,  2048, 512);
  transpose_cvt<<<dim3(16, 8, 1), 256, 0, stream>>>(W1, W1T, 512, 1024);
  transpose_cvt<<<dim3(8,  8, 1), 256, 0, stream>>>(W2, W2T, 512, 512);

  qk_gemm      <<<dim3(16, 16, 8), 256, 0, stream>>>(Qbf, Kbf, scoresP);
  softmax_rows <<<dim3(2048, 8),   256, 0, stream>>>(scoresP);
  pv_rms1      <<<dim3(256),       512, 0, stream>>>(scoresP, XT, x, n1w, hbf);
  ffn1         <<<dim3(8, 128),    256, 0, stream>>>(hbf, W1T, b1, gbuf);
  ffn2_rms2    <<<dim3(256),       512, 0, stream>>>(gbuf, W2T, b2, hbf, n2w, out);
}